// Round 3
// baseline (2912.916 us; speedup 1.0000x reference)
//
#include <hip/hip_runtime.h>
#include <hip/hip_bf16.h>

#define NN 100000
#define NE 1600000
#define EPW 8

typedef __hip_bfloat16 bf16;
typedef unsigned short u16;

__device__ __forceinline__ float b2f_raw(u16 u) {
    unsigned int w = ((unsigned int)u) << 16;
    float f; __builtin_memcpy(&f, &w, 4); return f;
}
__device__ __forceinline__ float eluf(float x) { return x > 0.f ? x : expm1f(x); }

// canonical weight block offsets (f32 words)
#define OFF_ENC_W0 0
#define OFF_ENC_B0 192
#define OFF_ENC_W1 256
#define OFF_ENC_B1 4352
#define OFF_DEC_W0 4416
#define OFF_DEC_B0 8512
#define OFF_DEC_W1 8576
#define OFF_DEC_B1 8768
#define OFF_EW0    8832     // raw [2,195,64]
#define OFF_EB0    33792
#define OFF_EW1    33920
#define OFF_EB1    42112
#define OFF_NW0    42240
#define OFF_NB0    58624
#define OFF_NW1    58752
#define OFF_NB1    66944
#define OFF_CA     67072
#define OFF_CB     75264
#define WBLK_WORDS 83456

// ---- dtype probe: flags[0]=1 if float arrays are f32 (else bf16);
//      flags[1]=1 if edge_index is int64 (else int32).
__global__ void probe_kernel(const u16* __restrict__ xr,
                             const unsigned int* __restrict__ er,
                             int* __restrict__ flags) {
    if (blockIdx.x == 0 && threadIdx.x == 0) {
        int wild = 0;
        for (int j = 0; j < 256; ++j) {
            int e = (xr[j] >> 7) & 0xFF;           // bf16-interp exponent field
            if (e > 140 || (e < 90 && e != 0)) wild++;  // |v|>2^13 or <2^-37: impossible for N(0,1) bf16
        }
        flags[0] = (wild > 16) ? 1 : 0;
        int oddnz = 0;
        for (int j = 1; j < 256; j += 2) if (er[j] != 0u) oddnz++;
        flags[1] = (oddnz < 8) ? 1 : 0;             // int64 high words are all zero
    }
}

struct WPtrs { const void* p[16]; };

__global__ void canon_weights(WPtrs wp, float* __restrict__ wblk,
                              const int* __restrict__ flags) {
    const int offs[16] = {OFF_ENC_W0, OFF_ENC_B0, OFF_ENC_W1, OFF_ENC_B1,
                          OFF_DEC_W0, OFF_DEC_B0, OFF_DEC_W1, OFF_DEC_B1,
                          OFF_EW0, OFF_EB0, OFF_EW1, OFF_EB1,
                          OFF_NW0, OFF_NB0, OFF_NW1, OFF_NB1};
    const int ns[16]   = {192, 64, 4096, 64, 4096, 64, 192, 3,
                          24960, 128, 8192, 128, 16384, 128, 8192, 128};
    int t = blockIdx.y;
    int i = blockIdx.x * blockDim.x + threadIdx.x;
    if (i >= ns[t]) return;
    const void* s = wp.p[t];
    float v = flags[0] ? ((const float*)s)[i] : b2f_raw(((const u16*)s)[i]);
    wblk[offs[t] + i] = v;
}

__global__ void canon_xp(const void* __restrict__ xsrc, const void* __restrict__ psrc,
                         float* __restrict__ xf, float* __restrict__ pf,
                         const int* __restrict__ flags) {
    int i = blockIdx.x * 256 + threadIdx.x;
    if (i >= NN * 3) return;
    const void* s = blockIdx.y ? psrc : xsrc;
    float* d = blockIdx.y ? pf : xf;
    d[i] = flags[0] ? ((const float*)s)[i] : b2f_raw(((const u16*)s)[i]);
}

__global__ void canon_ei(const void* __restrict__ esrc, int* __restrict__ eic,
                         const int* __restrict__ flags) {
    int i = blockIdx.x * 256 + threadIdx.x;
    if (i >= 2 * NE) return;
    eic[i] = flags[1] ? (int)((const long long*)esrc)[i] : ((const int*)esrc)[i];
}

// fold layer-1 edge weights: xn*Wa + xo*Wb + (xn-xo)*Wc = xn*(Wa+Wc) + xo*(Wb-Wc)
__global__ void prep_cacb(float* __restrict__ wblk) {
    int idx = blockIdx.x * 256 + threadIdx.x;
    if (idx >= 8192) return;
    int l = idx >> 12, r = idx & 4095, k = r >> 6, c = r & 63;
    const float* W = wblk + OFF_EW0 + l * 12480;
    float wa = W[k * 64 + c], wb = W[(64 + k) * 64 + c], wc = W[(128 + k) * 64 + c];
    wblk[OFF_CA + idx] = wa + wc;
    wblk[OFF_CB + idx] = wb - wc;
}

__global__ void zero_agg(float* __restrict__ agg) {
    int i = blockIdx.x * 256 + threadIdx.x;
    if (i < NN * 16) ((float4*)agg)[i] = make_float4(0.f, 0.f, 0.f, 0.f);
}

__global__ void encoder_kernel(const float* __restrict__ xf,
                               const float* __restrict__ wblk,
                               float* __restrict__ h) {
    __shared__ __attribute__((aligned(16))) float t[4][64];
    int ty = threadIdx.y, c = threadIdx.x;
    int n = blockIdx.x * 4 + ty;
    const float* W0 = wblk + OFF_ENC_W0;
    const float* b0 = wblk + OFF_ENC_B0;
    const float* W1 = wblk + OFF_ENC_W1;
    const float* b1 = wblk + OFF_ENC_B1;
    float acc = 0.f;
    if (n < NN) {
        acc = b0[c] + xf[n * 3 + 0] * W0[c] + xf[n * 3 + 1] * W0[64 + c]
                    + xf[n * 3 + 2] * W0[128 + c];
        acc = eluf(acc);
    }
    t[ty][c] = acc;
    __syncthreads();
    if (n >= NN) return;
    float a2 = b1[c];
#pragma unroll
    for (int k = 0; k < 64; ++k) a2 += t[ty][k] * W1[k * 64 + c];
    h[(size_t)n * 64 + c] = a2;
}

// Edge MLP + scatter-add. 3 waves/block; each wave processes EPW=8 edges per
// iteration with weights in LDS (staged once) and wave-private x-staging
// (no barriers in the loop: LDS ops of one wave execute in order).
__global__ __launch_bounds__(192) void edge_kernel(
    const float* __restrict__ h, const float* __restrict__ pf,
    const int* __restrict__ eic,
    const float* __restrict__ cAp, const float* __restrict__ cBp,
    const float* __restrict__ posWp, const float* __restrict__ eb0p,
    const float* __restrict__ w1p, const float* __restrict__ eb1p,
    float* __restrict__ agg, int nwaves) {
    __shared__ float sA[4096];                 // 16 KB
    __shared__ float sB[4096];                 // 16 KB
    __shared__ float sW1[4096];                // 16 KB
    __shared__ __attribute__((aligned(16))) float sX[3][64][EPW];  // 6 KB (xn; then reused as-is)
    __shared__ __attribute__((aligned(16))) float sO[3][64][EPW];  // 6 KB (xo, then h1)
    __shared__ float sPD[3][EPW][4];           // 384 B
    int tid = threadIdx.x, wid = tid >> 6, c = tid & 63;
    for (int i = tid; i < 4096; i += 192) { sA[i] = cAp[i]; sB[i] = cBp[i]; sW1[i] = w1p[i]; }
    __syncthreads();
    float rb0 = eb0p[c], rb1 = eb1p[c];
    float rp0 = posWp[c], rp1 = posWp[64 + c], rp2 = posWp[128 + c];

    for (int g = blockIdx.x * 3 + wid; g < NE / EPW; g += nwaves) {
        int e0 = g * EPW;
        int idxv = 0;
        if (c < 8) idxv = eic[e0 + c];
        else if (c < 16) idxv = eic[NE + e0 + (c - 8)];
        int srcs[EPW], dsts[EPW];
#pragma unroll
        for (int j = 0; j < EPW; ++j) {
            srcs[j] = __shfl(idxv, j);
            dsts[j] = __shfl(idxv, 8 + j);
            if ((unsigned)srcs[j] >= NN) srcs[j] = 0;
            if ((unsigned)dsts[j] >= NN) dsts[j] = 0;
        }
        float vn[EPW], vo[EPW];
#pragma unroll
        for (int j = 0; j < EPW; ++j) {
            vn[j] = h[(size_t)srcs[j] * 64 + c];
            vo[j] = h[(size_t)dsts[j] * 64 + c];
        }
        *(float4*)&sX[wid][c][0] = make_float4(vn[0], vn[1], vn[2], vn[3]);
        *(float4*)&sX[wid][c][4] = make_float4(vn[4], vn[5], vn[6], vn[7]);
        *(float4*)&sO[wid][c][0] = make_float4(vo[0], vo[1], vo[2], vo[3]);
        *(float4*)&sO[wid][c][4] = make_float4(vo[4], vo[5], vo[6], vo[7]);
        if (c < 24) {
            int j = c / 3, d = c - j * 3;
            sPD[wid][j][d] = pf[(size_t)srcs[j] * 3 + d] - pf[(size_t)dsts[j] * 3 + d];
        }
        float acc[EPW];
#pragma unroll
        for (int j = 0; j < EPW; ++j) acc[j] = rb0;
#pragma unroll 8
        for (int k = 0; k < 64; ++k) {
            float wA = sA[k * 64 + c], wB = sB[k * 64 + c];
            float4 a0 = *(const float4*)&sX[wid][k][0];
            float4 a1 = *(const float4*)&sX[wid][k][4];
            float4 b0 = *(const float4*)&sO[wid][k][0];
            float4 b1 = *(const float4*)&sO[wid][k][4];
            acc[0] += wA * a0.x + wB * b0.x;  acc[1] += wA * a0.y + wB * b0.y;
            acc[2] += wA * a0.z + wB * b0.z;  acc[3] += wA * a0.w + wB * b0.w;
            acc[4] += wA * a1.x + wB * b1.x;  acc[5] += wA * a1.y + wB * b1.y;
            acc[6] += wA * a1.z + wB * b1.z;  acc[7] += wA * a1.w + wB * b1.w;
        }
#pragma unroll
        for (int j = 0; j < EPW; ++j) {
            acc[j] += sPD[wid][j][0] * rp0 + sPD[wid][j][1] * rp1 + sPD[wid][j][2] * rp2;
            acc[j] = eluf(acc[j]);
        }
        *(float4*)&sO[wid][c][0] = make_float4(acc[0], acc[1], acc[2], acc[3]);
        *(float4*)&sO[wid][c][4] = make_float4(acc[4], acc[5], acc[6], acc[7]);
        float a2[EPW];
#pragma unroll
        for (int j = 0; j < EPW; ++j) a2[j] = rb1;
#pragma unroll 8
        for (int k = 0; k < 64; ++k) {
            float w1 = sW1[k * 64 + c];
            float4 p0 = *(const float4*)&sO[wid][k][0];
            float4 p1 = *(const float4*)&sO[wid][k][4];
            a2[0] += w1 * p0.x;  a2[1] += w1 * p0.y;  a2[2] += w1 * p0.z;  a2[3] += w1 * p0.w;
            a2[4] += w1 * p1.x;  a2[5] += w1 * p1.y;  a2[6] += w1 * p1.z;  a2[7] += w1 * p1.w;
        }
#pragma unroll
        for (int j = 0; j < EPW; ++j)
            atomicAdd(&agg[(size_t)dsts[j] * 64 + c], a2[j]);
    }
}

__global__ void node_kernel(float* __restrict__ h, const float* __restrict__ agg,
                            const float* __restrict__ wblk, int l) {
    __shared__ __attribute__((aligned(16))) float hn[4][64];
    __shared__ __attribute__((aligned(16))) float an[4][64];
    __shared__ __attribute__((aligned(16))) float u1[4][64];
    int ty = threadIdx.y, c = threadIdx.x;
    int n = blockIdx.x * 4 + ty;
    const float* W0 = wblk + OFF_NW0 + l * 8192;
    const float* b0 = wblk + OFF_NB0 + l * 64;
    const float* W1 = wblk + OFF_NW1 + l * 4096;
    const float* b1 = wblk + OFF_NB1 + l * 64;
    float hv = 0.f, av = 0.f;
    if (n < NN) { hv = h[(size_t)n * 64 + c]; av = agg[(size_t)n * 64 + c]; }
    hn[ty][c] = hv; an[ty][c] = av;
    __syncthreads();
    float a = b0[c];
#pragma unroll
    for (int k = 0; k < 64; ++k)
        a += hn[ty][k] * W0[k * 64 + c] + an[ty][k] * W0[(64 + k) * 64 + c];
    u1[ty][c] = eluf(a);
    __syncthreads();
    float a2 = b1[c];
#pragma unroll
    for (int k = 0; k < 64; ++k) a2 += u1[ty][k] * W1[k * 64 + c];
    if (n < NN) h[(size_t)n * 64 + c] = hv + a2;
}

__global__ void decoder_kernel(const float* __restrict__ h,
                               const float* __restrict__ wblk,
                               void* __restrict__ out, const int* __restrict__ flags) {
    __shared__ __attribute__((aligned(16))) float hn[4][64];
    __shared__ __attribute__((aligned(16))) float d1[4][64];
    int ty = threadIdx.y, c = threadIdx.x;
    int n = blockIdx.x * 4 + ty;
    const float* W0 = wblk + OFF_DEC_W0;
    const float* b0 = wblk + OFF_DEC_B0;
    const float* W1 = wblk + OFF_DEC_W1;
    const float* b1 = wblk + OFF_DEC_B1;
    hn[ty][c] = (n < NN) ? h[(size_t)n * 64 + c] : 0.f;
    __syncthreads();
    float a = b0[c];
#pragma unroll
    for (int k = 0; k < 64; ++k) a += hn[ty][k] * W0[k * 64 + c];
    d1[ty][c] = eluf(a);
    __syncthreads();
    if (n < NN && c < 3) {
        float a2 = b1[c];
#pragma unroll
        for (int k = 0; k < 64; ++k) a2 += d1[ty][k] * W1[k * 3 + c];
        if (flags[0]) ((float*)out)[n * 3 + c] = a2;
        else          ((bf16*)out)[n * 3 + c] = __float2bfloat16(a2);
    }
}

extern "C" void kernel_launch(void* const* d_in, const int* in_sizes, int n_in,
                              void* d_out, int out_size, void* d_ws, size_t ws_size,
                              hipStream_t stream) {
    // Workspace layout (f32 words), total ~66.8 MB
    int*   flags = (int*)d_ws;                   // 16
    float* wblk  = (float*)d_ws + 16;            // 83456
    float* xf    = wblk + WBLK_WORDS;            // 300000
    float* pf    = xf + 300000;                  // 300000
    int*   eic   = (int*)(pf + 300000);          // 3200000
    float* agg   = (float*)(eic + 3200000);      // 6400000
    float* hbuf  = agg + (size_t)6400000;        // 6400000

    probe_kernel<<<1, 64, 0, stream>>>((const u16*)d_in[0],
                                       (const unsigned int*)d_in[2], flags);

    WPtrs wp;
    wp.p[0] = d_in[3];  wp.p[1] = d_in[4];  wp.p[2] = d_in[5];  wp.p[3] = d_in[6];
    wp.p[4] = d_in[7];  wp.p[5] = d_in[8];  wp.p[6] = d_in[9];  wp.p[7] = d_in[10];
    wp.p[8] = d_in[11]; wp.p[9] = d_in[12]; wp.p[10] = d_in[13]; wp.p[11] = d_in[14];
    wp.p[12] = d_in[15]; wp.p[13] = d_in[16]; wp.p[14] = d_in[17]; wp.p[15] = d_in[18];
    canon_weights<<<dim3(98, 16), 256, 0, stream>>>(wp, wblk, flags);
    canon_xp<<<dim3(1172, 2), 256, 0, stream>>>(d_in[0], d_in[1], xf, pf, flags);
    canon_ei<<<12500, 256, 0, stream>>>(d_in[2], eic, flags);
    prep_cacb<<<32, 256, 0, stream>>>(wblk);

    dim3 blk(64, 4);
    encoder_kernel<<<25000, blk, 0, stream>>>(xf, wblk, hbuf);

    const int EDGE_BLOCKS = 2048;
    const int NWAVES = EDGE_BLOCKS * 3;
    for (int l = 0; l < 2; ++l) {
        zero_agg<<<6250, 256, 0, stream>>>(agg);
        edge_kernel<<<EDGE_BLOCKS, 192, 0, stream>>>(
            hbuf, pf, eic,
            wblk + OFF_CA + l * 4096, wblk + OFF_CB + l * 4096,
            wblk + OFF_EW0 + l * 12480 + 192 * 64, wblk + OFF_EB0 + l * 64,
            wblk + OFF_EW1 + l * 4096, wblk + OFF_EB1 + l * 64,
            agg, NWAVES);
        node_kernel<<<25000, blk, 0, stream>>>(hbuf, agg, wblk, l);
    }

    decoder_kernel<<<25000, blk, 0, stream>>>(hbuf, wblk, d_out, flags);
}

// Round 4
// 1241.409 us; speedup vs baseline: 2.3465x; 2.3465x over previous
//
#include <hip/hip_runtime.h>
#include <hip/hip_bf16.h>

#define NN 100000
#define NE 1600000

typedef __hip_bfloat16 bf16;
typedef unsigned short u16;
typedef short bshort8 __attribute__((ext_vector_type(8)));
typedef float f32x4 __attribute__((ext_vector_type(4)));

__device__ __forceinline__ float b2f_raw(u16 u) {
    unsigned int w = ((unsigned int)u) << 16;
    float f; __builtin_memcpy(&f, &w, 4); return f;
}
__device__ __forceinline__ u16 f2bu(float f) {
    bf16 h = __float2bfloat16(f); u16 u; __builtin_memcpy(&u, &h, 2); return u;
}
__device__ __forceinline__ float eluf(float x) { return x > 0.f ? x : expm1f(x); }
__device__ __forceinline__ bshort8 u4_to_s8(uint4 v) {
    union { uint4 u; bshort8 s; } x; x.u = v; return x.s;
}

// canonical weight block offsets (f32 words)
#define OFF_ENC_W0 0
#define OFF_ENC_B0 192
#define OFF_ENC_W1 256
#define OFF_ENC_B1 4352
#define OFF_DEC_W0 4416
#define OFF_DEC_B0 8512
#define OFF_DEC_W1 8576
#define OFF_DEC_B1 8768
#define OFF_EW0    8832     // raw [2,195,64]
#define OFF_EB0    33792
#define OFF_EW1    33920
#define OFF_EB1    42112
#define OFF_NW0    42240
#define OFF_NB0    58624
#define OFF_NW1    58752
#define OFF_NB1    66944
#define OFF_CA     67072
#define OFF_CB     75264
#define WBLK_WORDS 83456

// ---- dtype probe: flags[0]=1 if float arrays are f32 (else bf16);
//      flags[1]=1 if edge_index is int64 (else int32).
__global__ void probe_kernel(const u16* __restrict__ xr,
                             const unsigned int* __restrict__ er,
                             int* __restrict__ flags) {
    if (blockIdx.x == 0 && threadIdx.x == 0) {
        int wild = 0;
        for (int j = 0; j < 256; ++j) {
            int e = (xr[j] >> 7) & 0xFF;
            if (e > 140 || (e < 90 && e != 0)) wild++;
        }
        flags[0] = (wild > 16) ? 1 : 0;
        int oddnz = 0;
        for (int j = 1; j < 256; j += 2) if (er[j] != 0u) oddnz++;
        flags[1] = (oddnz < 8) ? 1 : 0;
    }
}

struct WPtrs { const void* p[16]; };

__global__ void canon_weights(WPtrs wp, float* __restrict__ wblk,
                              const int* __restrict__ flags) {
    const int offs[16] = {OFF_ENC_W0, OFF_ENC_B0, OFF_ENC_W1, OFF_ENC_B1,
                          OFF_DEC_W0, OFF_DEC_B0, OFF_DEC_W1, OFF_DEC_B1,
                          OFF_EW0, OFF_EB0, OFF_EW1, OFF_EB1,
                          OFF_NW0, OFF_NB0, OFF_NW1, OFF_NB1};
    const int ns[16]   = {192, 64, 4096, 64, 4096, 64, 192, 3,
                          24960, 128, 8192, 128, 16384, 128, 8192, 128};
    int t = blockIdx.y;
    int i = blockIdx.x * blockDim.x + threadIdx.x;
    if (i >= ns[t]) return;
    const void* s = wp.p[t];
    float v = flags[0] ? ((const float*)s)[i] : b2f_raw(((const u16*)s)[i]);
    wblk[offs[t] + i] = v;
}

__global__ void canon_xp(const void* __restrict__ xsrc, const void* __restrict__ psrc,
                         float* __restrict__ xf, float* __restrict__ pf,
                         const int* __restrict__ flags) {
    int i = blockIdx.x * 256 + threadIdx.x;
    if (i >= NN * 3) return;
    const void* s = blockIdx.y ? psrc : xsrc;
    float* d = blockIdx.y ? pf : xf;
    d[i] = flags[0] ? ((const float*)s)[i] : b2f_raw(((const u16*)s)[i]);
}

// fold layer-1 edge weights: xn*Wa + xo*Wb + (xn-xo)*Wc = xn*(Wa+Wc) + xo*(Wb-Wc)
__global__ void prep_cacb(float* __restrict__ wblk) {
    int idx = blockIdx.x * 256 + threadIdx.x;
    if (idx >= 8192) return;
    int l = idx >> 12, r = idx & 4095, k = r >> 6, c = r & 63;
    const float* W = wblk + OFF_EW0 + l * 12480;
    float wa = W[k * 64 + c], wb = W[(64 + k) * 64 + c], wc = W[(128 + k) * 64 + c];
    wblk[OFF_CA + idx] = wa + wc;
    wblk[OFF_CB + idx] = wb - wc;
}

// Pre-swizzle edge-MLP weights into MFMA B-fragment order (bf16).
// B-frag for 16x16x32: lane l holds B[k = ks*32 + (l>>4)*8 + j][n = nt*16 + (l&15)].
// swz layout: B1[2][5ks][4nt][64][8] then B2[2][2ks][4nt][64][8]  (u16 units)
__global__ void prep_swz(const float* __restrict__ wblk, u16* __restrict__ swz) {
    int t = blockIdx.x * 256 + threadIdx.x;
    if (t < 20480) {
        int l = t / 10240, r = t % 10240;
        int ks = r >> 11, lane = (r >> 3) & 63, j = r & 7;
        int nt = (r >> 9) & 3;
        int k = ks * 32 + (lane >> 4) * 8 + j;
        int n = nt * 16 + (lane & 15);
        float v = 0.f;
        if (k < 64)       v = wblk[OFF_CA + l * 4096 + k * 64 + n];
        else if (k < 128) v = wblk[OFF_CB + l * 4096 + (k - 64) * 64 + n];
        else if (k < 131) v = wblk[OFF_EW0 + l * 12480 + (192 + (k - 128)) * 64 + n];
        swz[l * 10240 + r] = f2bu(v);
    } else if (t < 20480 + 8192) {
        int t2 = t - 20480;
        int l = t2 / 4096, r = t2 % 4096;
        int ks = r >> 11, lane = (r >> 3) & 63, j = r & 7;
        int nt = (r >> 9) & 3;
        int k = ks * 32 + (lane >> 4) * 8 + j;
        int n = nt * 16 + (lane & 15);
        swz[20480 + l * 4096 + r] = f2bu(wblk[OFF_EW1 + l * 4096 + k * 64 + n]);
    }
}

__global__ void zero_agg(float* __restrict__ agg) {
    int i = blockIdx.x * 256 + threadIdx.x;
    if (i < NN * 16) ((float4*)agg)[i] = make_float4(0.f, 0.f, 0.f, 0.f);
}

__global__ void encoder_kernel(const float* __restrict__ xf,
                               const float* __restrict__ wblk,
                               float* __restrict__ h, u16* __restrict__ h2) {
    __shared__ __attribute__((aligned(16))) float t[4][64];
    int ty = threadIdx.y, c = threadIdx.x;
    int n = blockIdx.x * 4 + ty;
    const float* W0 = wblk + OFF_ENC_W0;
    const float* b0 = wblk + OFF_ENC_B0;
    const float* W1 = wblk + OFF_ENC_W1;
    const float* b1 = wblk + OFF_ENC_B1;
    float acc = 0.f;
    if (n < NN) {
        acc = b0[c] + xf[n * 3 + 0] * W0[c] + xf[n * 3 + 1] * W0[64 + c]
                    + xf[n * 3 + 2] * W0[128 + c];
        acc = eluf(acc);
    }
    t[ty][c] = acc;
    __syncthreads();
    if (n >= NN) return;
    float a2 = b1[c];
#pragma unroll
    for (int k = 0; k < 64; ++k) a2 += t[ty][k] * W1[k * 64 + c];
    h[(size_t)n * 64 + c] = a2;
    h2[(size_t)n * 64 + c] = f2bu(a2);
}

// MFMA edge kernel: 1 wave = 16 edges/iter. A-frags gathered directly from
// bf16 h rows (16B/lane). Weights pre-swizzled in LDS. pos-diff folded in as
// K-step 4 (K padded 131->160). Layer1->layer2 via per-wave LDS transpose
// (in-order wave LDS, no barrier). Scatter-add f32 atomics.
__global__ __launch_bounds__(256) void edge_mfma(
    const u16* __restrict__ h2, const float* __restrict__ pf,
    const int* __restrict__ eiraw,
    const u16* __restrict__ swB1, const u16* __restrict__ swB2,
    const float* __restrict__ eb0p, const float* __restrict__ eb1p,
    float* __restrict__ agg, const int* __restrict__ flags,
    int ngroups, int nwaves) {
    __shared__ __attribute__((aligned(16))) u16 sB1[10240];  // 20 KB
    __shared__ __attribute__((aligned(16))) u16 sB2[4096];   // 8 KB
    __shared__ __attribute__((aligned(16))) u16 sP[4][16 * 72]; // 9 KB transpose buf
    int tid = threadIdx.x;
    for (int i = tid; i < 1280; i += 256) ((uint4*)sB1)[i] = ((const uint4*)swB1)[i];
    for (int i = tid; i < 512; i += 256)  ((uint4*)sB2)[i] = ((const uint4*)swB2)[i];
    __syncthreads();
    int wid = tid >> 6, l = tid & 63;
    int m16 = l & 15, half = l >> 4;
    int estride = flags[1] ? 2 : 1;
    float bias1[4], bias2[4];
#pragma unroll
    for (int nt = 0; nt < 4; ++nt) {
        bias1[nt] = eb0p[nt * 16 + m16];
        bias2[nt] = eb1p[nt * 16 + m16];
    }
    u16* myP = sP[wid];
    const bshort8* B1 = (const bshort8*)sB1;
    const bshort8* B2 = (const bshort8*)sB2;

    for (int g = blockIdx.x * 4 + wid; g < ngroups; g += nwaves) {
        int e0 = g * 16;
        int srcm = eiraw[(size_t)(e0 + m16) * estride];
        int dstm = eiraw[((size_t)NE + e0 + m16) * estride];
        if ((unsigned)srcm >= NN) srcm = 0;
        if ((unsigned)dstm >= NN) dstm = 0;
        const uint4* rs = (const uint4*)(h2 + (size_t)srcm * 64);
        const uint4* rd = (const uint4*)(h2 + (size_t)dstm * 64);
        uint4 afr[5];
        afr[0] = rs[half];      // k 0..31   (hs)
        afr[1] = rs[half + 4];  // k 32..63
        afr[2] = rd[half];      // k 64..95  (hd)
        afr[3] = rd[half + 4];  // k 96..127
        afr[4] = make_uint4(0, 0, 0, 0);   // k 128..159 (pd | zeros)
        if (half == 0) {
            float p0 = pf[srcm * 3 + 0] - pf[dstm * 3 + 0];
            float p1 = pf[srcm * 3 + 1] - pf[dstm * 3 + 1];
            float p2 = pf[srcm * 3 + 2] - pf[dstm * 3 + 2];
            afr[4].x = (unsigned)f2bu(p0) | ((unsigned)f2bu(p1) << 16);
            afr[4].y = (unsigned)f2bu(p2);
        }
        f32x4 acc[4];
#pragma unroll
        for (int nt = 0; nt < 4; ++nt)
            acc[nt] = f32x4{bias1[nt], bias1[nt], bias1[nt], bias1[nt]};
#pragma unroll
        for (int ks = 0; ks < 5; ++ks) {
            bshort8 av = u4_to_s8(afr[ks]);
#pragma unroll
            for (int nt = 0; nt < 4; ++nt)
                acc[nt] = __builtin_amdgcn_mfma_f32_16x16x32_bf16(
                    av, B1[(ks * 4 + nt) * 64 + l], acc[nt], 0, 0, 0);
        }
        // ELU + transpose to A-layout via LDS (C/D: row=(l>>4)*4+r, col=nt*16+m16)
#pragma unroll
        for (int nt = 0; nt < 4; ++nt) {
#pragma unroll
            for (int r = 0; r < 4; ++r) {
                float v = acc[nt][r];
                v = v > 0.f ? v : expm1f(v);
                myP[(half * 4 + r) * 72 + nt * 16 + m16] = f2bu(v);
            }
        }
        f32x4 acc2[4];
#pragma unroll
        for (int nt = 0; nt < 4; ++nt)
            acc2[nt] = f32x4{bias2[nt], bias2[nt], bias2[nt], bias2[nt]};
#pragma unroll
        for (int ks = 0; ks < 2; ++ks) {
            bshort8 av = *(const bshort8*)(myP + m16 * 72 + ks * 32 + half * 8);
#pragma unroll
            for (int nt = 0; nt < 4; ++nt)
                acc2[nt] = __builtin_amdgcn_mfma_f32_16x16x32_bf16(
                    av, B2[(ks * 4 + nt) * 64 + l], acc2[nt], 0, 0, 0);
        }
        int dstr[4];
#pragma unroll
        for (int r = 0; r < 4; ++r) dstr[r] = __shfl(dstm, half * 4 + r);
#pragma unroll
        for (int nt = 0; nt < 4; ++nt)
#pragma unroll
            for (int r = 0; r < 4; ++r)
                atomicAdd(&agg[(size_t)dstr[r] * 64 + nt * 16 + m16], acc2[nt][r]);
    }
}

__global__ void node_kernel(float* __restrict__ h, u16* __restrict__ h2,
                            const float* __restrict__ agg,
                            const float* __restrict__ wblk, int l) {
    __shared__ __attribute__((aligned(16))) float hn[4][64];
    __shared__ __attribute__((aligned(16))) float an[4][64];
    __shared__ __attribute__((aligned(16))) float u1[4][64];
    int ty = threadIdx.y, c = threadIdx.x;
    int n = blockIdx.x * 4 + ty;
    const float* W0 = wblk + OFF_NW0 + l * 8192;
    const float* b0 = wblk + OFF_NB0 + l * 64;
    const float* W1 = wblk + OFF_NW1 + l * 4096;
    const float* b1 = wblk + OFF_NB1 + l * 64;
    float hv = 0.f, av = 0.f;
    if (n < NN) { hv = h[(size_t)n * 64 + c]; av = agg[(size_t)n * 64 + c]; }
    hn[ty][c] = hv; an[ty][c] = av;
    __syncthreads();
    float a = b0[c];
#pragma unroll
    for (int k = 0; k < 64; ++k)
        a += hn[ty][k] * W0[k * 64 + c] + an[ty][k] * W0[(64 + k) * 64 + c];
    u1[ty][c] = eluf(a);
    __syncthreads();
    float a2 = b1[c];
#pragma unroll
    for (int k = 0; k < 64; ++k) a2 += u1[ty][k] * W1[k * 64 + c];
    if (n < NN) {
        float nh = hv + a2;
        h[(size_t)n * 64 + c] = nh;
        h2[(size_t)n * 64 + c] = f2bu(nh);
    }
}

__global__ void decoder_kernel(const float* __restrict__ h,
                               const float* __restrict__ wblk,
                               void* __restrict__ out, const int* __restrict__ flags) {
    __shared__ __attribute__((aligned(16))) float hn[4][64];
    __shared__ __attribute__((aligned(16))) float d1[4][64];
    int ty = threadIdx.y, c = threadIdx.x;
    int n = blockIdx.x * 4 + ty;
    const float* W0 = wblk + OFF_DEC_W0;
    const float* b0 = wblk + OFF_DEC_B0;
    const float* W1 = wblk + OFF_DEC_W1;
    const float* b1 = wblk + OFF_DEC_B1;
    hn[ty][c] = (n < NN) ? h[(size_t)n * 64 + c] : 0.f;
    __syncthreads();
    float a = b0[c];
#pragma unroll
    for (int k = 0; k < 64; ++k) a += hn[ty][k] * W0[k * 64 + c];
    d1[ty][c] = eluf(a);
    __syncthreads();
    if (n < NN && c < 3) {
        float a2 = b1[c];
#pragma unroll
        for (int k = 0; k < 64; ++k) a2 += d1[ty][k] * W1[k * 3 + c];
        if (flags[0]) ((float*)out)[n * 3 + c] = a2;
        else          ((bf16*)out)[n * 3 + c] = __float2bfloat16(a2);
    }
}

extern "C" void kernel_launch(void* const* d_in, const int* in_sizes, int n_in,
                              void* d_out, int out_size, void* d_ws, size_t ws_size,
                              hipStream_t stream) {
    // Workspace (f32 words), total ~66.8 MB (same footprint as passing R3):
    int*   flags = (int*)d_ws;                       // 16
    float* wblk  = (float*)d_ws + 16;                // 83456
    u16*   swz   = (u16*)(wblk + WBLK_WORDS);        // 28672 u16 = 14336 words
    float* xf    = wblk + WBLK_WORDS + 14336;        // 300000
    float* pf    = xf + 300000;                      // 300000
    float* agg   = pf + 300000;                      // 6.4M
    float* hbuf  = agg + (size_t)6400000;            // 6.4M
    u16*   h2    = (u16*)(hbuf + (size_t)6400000);   // 6.4M u16

    probe_kernel<<<1, 64, 0, stream>>>((const u16*)d_in[0],
                                       (const unsigned int*)d_in[2], flags);

    WPtrs wp;
    wp.p[0] = d_in[3];  wp.p[1] = d_in[4];  wp.p[2] = d_in[5];  wp.p[3] = d_in[6];
    wp.p[4] = d_in[7];  wp.p[5] = d_in[8];  wp.p[6] = d_in[9];  wp.p[7] = d_in[10];
    wp.p[8] = d_in[11]; wp.p[9] = d_in[12]; wp.p[10] = d_in[13]; wp.p[11] = d_in[14];
    wp.p[12] = d_in[15]; wp.p[13] = d_in[16]; wp.p[14] = d_in[17]; wp.p[15] = d_in[18];
    canon_weights<<<dim3(98, 16), 256, 0, stream>>>(wp, wblk, flags);
    canon_xp<<<dim3(1172, 2), 256, 0, stream>>>(d_in[0], d_in[1], xf, pf, flags);
    prep_cacb<<<32, 256, 0, stream>>>(wblk);
    prep_swz<<<112, 256, 0, stream>>>(wblk, swz);

    dim3 blk(64, 4);
    encoder_kernel<<<25000, blk, 0, stream>>>(xf, wblk, hbuf, h2);

    const int EDGE_BLOCKS = 1024;
    const int NWAVES = EDGE_BLOCKS * 4;
    const int NGROUPS = NE / 16;
    for (int l = 0; l < 2; ++l) {
        zero_agg<<<6250, 256, 0, stream>>>(agg);
        edge_mfma<<<EDGE_BLOCKS, 256, 0, stream>>>(
            h2, pf, (const int*)d_in[2],
            swz + (size_t)l * 10240, swz + 20480 + (size_t)l * 4096,
            wblk + OFF_EB0 + l * 64, wblk + OFF_EB1 + l * 64,
            agg, flags, NGROUPS, NWAVES);
        node_kernel<<<25000, blk, 0, stream>>>(hbuf, h2, agg, wblk, l);
    }

    decoder_kernel<<<25000, blk, 0, stream>>>(hbuf, wblk, d_out, flags);
}